// Round 4
// baseline (87.603 us; speedup 1.0000x reference)
//
#include <hip/hip_runtime.h>
#include <hip/hip_fp16.h>
#include <math.h>

// Problem constants (match reference)
#define NCURVES   256
#define GPER      64               // NUM_BEZIERS * NUM_SAMPLES = 2*32
#define NUM_G     (NCURVES*GPER)   // 16384
#define IMG_W     256
#define IMG_H     256
#define TILE      16
#define TILES_X   (IMG_W/TILE)     // 16
#define TILES_Y   (IMG_H/TILE)     // 16
#define NTILES    (TILES_X*TILES_Y)
#define REC_F     8                // floats per gaussian record (32 B: 2 float4)

#define A_MIN     3.0e-6f          // alpha cutoff for tile bbox
#define P_CUT     (-12.6f)         // per-pixel power cutoff (consistent with A_MIN)
#define T_EPS     1.0e-5f          // transmittance early-out (residual <= 1e-5)

#define SEGS      8                // depth slices (by gi range) -> cross-CU split
#define GSEG      (NUM_G/SEGS)     // 2048 gaussians per slice
#define GWAVE     (GSEG/4)         // 512 per scan wave (4 waves/block)
#define PF        4                // composite software-pipeline group size

// ---------------------------------------------------------------------------
// Kernel 1 (prep): UNCHANGED (verified round 3). 256 blocks x 64 threads.
// record: {mx,my,A,B},{C,alpha,rg(f16x2),cb(f16)}.
// ---------------------------------------------------------------------------
__global__ __launch_bounds__(GPER)
void prep(const float* __restrict__ ctrl,        // [256][10][2]
          const float* __restrict__ features,    // [256][3]
          const float* __restrict__ cholesky,    // [256][3]
          const float* __restrict__ opacity,     // [256]
          const float* __restrict__ depth,       // [256]
          float*       __restrict__ recs,        // [NUM_G][8]
          unsigned*    __restrict__ bbox)        // [NUM_G]
{
    int c   = blockIdx.x;
    int tid = threadIdx.x;          // 0..63 (exactly one wave)

    // ---- stable rank (matches stable argsort over 64x-repeated depths)
    float dc = depth[c];
    int r = 0;
    #pragma unroll
    for (int jj = 0; jj < 4; ++jj) {
        int j = tid + jj*64;
        float dj = depth[j];
        r += (dj < dc) || (dj == dc && j < c);
    }
    #pragma unroll
    for (int off = 32; off > 0; off >>= 1) r += __shfl_down(r, off, 64);
    r = __shfl(r, 0, 64);

    // ---- per-curve params
    float c0 = cholesky[3*c+0] + 0.5f;
    float c1 = cholesky[3*c+1];
    float c2 = cholesky[3*c+2] + 0.5f;
    float s00 = c0*c0;
    float s01 = c0*c1;
    float s11 = c1*c1 + c2*c2;
    float inv = 1.0f / (s00*s11 - s01*s01);
    float A  =  s11*inv;
    float Bc = -s01*inv;
    float Cc =  s00*inv;

    float cr = 1.0f/(1.0f + __expf(-features[3*c+0]));
    float cg = 1.0f/(1.0f + __expf(-features[3*c+1]));
    float cb = 1.0f/(1.0f + __expf(-features[3*c+2]));
    float al = 1.0f/(1.0f + __expf(-opacity[c]));

    float cut = fmaxf(2.0f*(__logf(al) - __logf(A_MIN)), 0.0f);
    float rx = sqrtf(cut * s00);
    float ry = sqrtf(cut * s11);

    // ---- bezier sample -> mean
    int k = tid >> 5;               // bezier segment 0/1
    int s = tid & 31;               // sample 0..31
    float t = 0.007f + (float)s * (0.986f/31.0f);
    float u = 1.0f - t;
    float t2=t*t, t3=t2*t, t4=t3*t, t5=t4*t;
    float u2=u*u, u3=u2*u, u4=u3*u, u5=u4*u;
    float w[6] = { u5, 5.0f*t*u4, 10.0f*t2*u3, 10.0f*t3*u2, 5.0f*t4*u, t5 };

    const float* cp = ctrl + c*20;
    float px = 0.0f, py = 0.0f;
    #pragma unroll
    for (int j = 0; j < 6; ++j) {
        int idx = (k*5 + j) % 10;   // seg0: 0..5 ; seg1: 5,6,7,8,9,0
        px += w[j]*cp[2*idx+0];
        py += w[j]*cp[2*idx+1];
    }
    float mx = (tanhf(px)*0.5f + 0.5f) * (float)IMG_W;
    float my = (tanhf(py)*0.5f + 0.5f) * (float)IMG_H;

    int gi = r*GPER + tid;          // depth-sorted gaussian index (stable ties)

    unsigned rg  = (unsigned)__half_as_ushort(__float2half_rn(cr))
                 | ((unsigned)__half_as_ushort(__float2half_rn(cg)) << 16);
    unsigned cbp = (unsigned)__half_as_ushort(__float2half_rn(cb));

    float4* o4 = (float4*)(recs + (size_t)gi*REC_F);
    o4[0] = make_float4(mx, my, A, Bc);
    o4[1] = make_float4(Cc, al, __uint_as_float(rg), __uint_as_float(cbp));

    int tx0 = min(max((int)floorf((mx - rx) * (1.0f/TILE)), 0), TILES_X-1);
    int tx1 = min(max((int)floorf((mx + rx) * (1.0f/TILE)), 0), TILES_X-1);
    int ty0 = min(max((int)floorf((my - ry) * (1.0f/TILE)), 0), TILES_Y-1);
    int ty1 = min(max((int)floorf((my + ry) * (1.0f/TILE)), 0), TILES_Y-1);
    bbox[gi] = (unsigned)tx0 | ((unsigned)ty0<<8) | ((unsigned)tx1<<16) | ((unsigned)ty1<<24);
}

// ---------------------------------------------------------------------------
// Kernel 2 (render8): grid = (tile, gi-eighth) = 2048 blocks x 256 threads.
// Round-4 change: the composite loop is SOFTWARE-PIPELINED. Round 3 was
// latency-bound (~200 cyc/iter: flat[j] LDS -> addr -> L2 load -> use, only
// unroll-2 deep; hot blocks end up alone on their SIMD with nothing to hide
// it). All list loads are independent -- only T-accumulation is serial -- so
// a 4-wide register double-buffer (static indices only, full unroll) makes
// it issue-bound (~30-40 cyc/iter). 16 float4 in flight; __launch_bounds__
// (256,4) caps VGPR at 128 -> 4 blocks/CU -> 2048 blocks in 2 rounds.
// ---------------------------------------------------------------------------
__global__ __launch_bounds__(256, 4)
void render8(const float*    __restrict__ recs,
             const unsigned* __restrict__ bbox,
             float4*         __restrict__ partial)   // [SEGS][IMG_H*IMG_W]
{
    __shared__ unsigned short flat[GSEG];   // 4 KB: ordered hit list (gi-local)
    __shared__ unsigned       wn[4];

    int tid   = threadIdx.x;
    int seg   = blockIdx.x & (SEGS-1);
    int tile  = blockIdx.x >> 3;            // 0..255
    int tilex = tile & (TILES_X-1);
    int tiley = tile >> 4;

    int lane = tid & 63;
    int wid  = tid >> 6;                    // 0..3
    unsigned long long lmask = (1ull << lane) - 1ull;

    int sbase = seg * GSEG;
    int gwave = wid * GWAVE;                // local base of this wave's subrange

    // ---- Phase 1a: predicate + count (no LDS writes yet)
    bool pr[8];
    int cnt = 0;
    {
        unsigned bb[8];
        #pragma unroll
        for (int u = 0; u < 8; ++u)
            bb[u] = bbox[sbase + gwave + u*64 + lane];
        #pragma unroll
        for (int u = 0; u < 8; ++u) {
            unsigned b = bb[u];
            pr[u] = (tilex >= (int)( b        & 0xff)) &
                    (tilex <= (int)((b >> 16) & 0xff)) &
                    (tiley >= (int)((b >>  8) & 0xff)) &
                    (tiley <= (int)((b >> 24) & 0xff));
            cnt += (int)__popcll(__ballot(pr[u] ? 1 : 0));
        }
    }
    if (lane == 0) wn[wid] = (unsigned)cnt;
    __syncthreads();

    unsigned p1 = wn[0], p2 = p1 + wn[1], p3 = p2 + wn[2];
    int total = (int)(p3 + wn[3]);

    // ---- Phase 1b: compact into flat ordered list
    if (total) {
        unsigned base = (wid == 0) ? 0u : (wid == 1) ? p1 : (wid == 2) ? p2 : p3;
        int off = 0;
        #pragma unroll
        for (int u = 0; u < 8; ++u) {
            unsigned long long m = __ballot(pr[u] ? 1 : 0);
            if (pr[u])
                flat[base + off + (int)__popcll(m & lmask)] =
                    (unsigned short)(gwave + u*64 + lane);
            off += (int)__popcll(m);
        }
    }
    __syncthreads();

    // ---- Phase 2: composite, software-pipelined from L2 (broadcast reads)
    int ix = tid & (TILE-1);
    int iy = tid >> 4;
    float pxf = (float)(tilex*TILE + ix) + 0.5f;
    float pyf = (float)(tiley*TILE + iy) + 0.5f;

    float T = 1.0f, accr = 0.0f, accg = 0.0f, accb = 0.0f;

    float4 c0[PF], c1[PF], n0[PF], n1[PF];

    // prologue: group 0 into current buffer
    #pragma unroll
    for (int u = 0; u < PF; ++u) {
        if (u < total) {
            const float4* rp = (const float4*)
                (recs + (size_t)(sbase + (int)flat[u])*REC_F);
            c0[u] = rp[0]; c1[u] = rp[1];
        }
    }

    #pragma unroll 1
    for (int base = 0; base < total; base += PF) {
        int nb = base + PF;
        // prefetch next group (independent loads, issued before any use)
        #pragma unroll
        for (int u = 0; u < PF; ++u) {
            if (nb + u < total) {
                const float4* rp = (const float4*)
                    (recs + (size_t)(sbase + (int)flat[nb + u])*REC_F);
                n0[u] = rp[0]; n1[u] = rp[1];
            }
        }
        // composite current group
        #pragma unroll
        for (int u = 0; u < PF; ++u) {
            if (base + u < total) {
                float4 r0 = c0[u];          // mx, my, A, B
                float4 r1 = c1[u];          // C, alpha, rg(f16x2), cb(f16)
                float dx = pxf - r0.x;
                float dy = pyf - r0.y;
                float p  = -0.5f*(r0.z*dx*dx + r1.x*dy*dy) - r0.w*dx*dy;
                if (p > P_CUT) {
                    float a = fminf(r1.y * __expf(p), 0.999f);
                    float wgt = a * T;
                    unsigned rg = __float_as_uint(r1.z);
                    accr += wgt * __half2float(__ushort_as_half((unsigned short)(rg & 0xffff)));
                    accg += wgt * __half2float(__ushort_as_half((unsigned short)(rg >> 16)));
                    accb += wgt * __half2float(__ushort_as_half((unsigned short)__float_as_uint(r1.w)));
                    T *= (1.0f - a);
                }
            }
        }
        // rotate buffers (register renaming, all static indices)
        #pragma unroll
        for (int u = 0; u < PF; ++u) { c0[u] = n0[u]; c1[u] = n1[u]; }

        // wave-level early-out: residual contribution bounded by T <= 1e-5
        if (!__any(T > T_EPS)) break;
    }

    int X = tilex*TILE + ix;
    int Y = tiley*TILE + iy;
    partial[(size_t)seg*(IMG_W*IMG_H) + (size_t)Y*IMG_W + X] =
        make_float4(accr, accg, accb, T);
}

// ---------------------------------------------------------------------------
// Kernel 3: combine the 8 depth-ordered slices front-to-back, + background,
// clamp, store. UNCHANGED (verified round 3).
// ---------------------------------------------------------------------------
__global__ __launch_bounds__(256)
void combine(const float4* __restrict__ partial,
             const float*  __restrict__ background,
             float*        __restrict__ out)
{
    int p = blockIdx.x * 256 + threadIdx.x;     // pixel 0..65535

    float accr = 0.0f, accg = 0.0f, accb = 0.0f, T = 1.0f;
    #pragma unroll
    for (int s = 0; s < SEGS; ++s) {
        float4 q = partial[(size_t)s*(IMG_W*IMG_H) + p];
        accr += T * q.x;
        accg += T * q.y;
        accb += T * q.z;
        T    *= q.w;
    }
    float r = fminf(fmaxf(accr + T*background[0], 0.0f), 1.0f);
    float g = fminf(fmaxf(accg + T*background[1], 0.0f), 1.0f);
    float b = fminf(fmaxf(accb + T*background[2], 0.0f), 1.0f);

    size_t oi = (size_t)p*3;
    out[oi+0] = r;
    out[oi+1] = g;
    out[oi+2] = b;
}

// ---------------------------------------------------------------------------
extern "C" void kernel_launch(void* const* d_in, const int* in_sizes, int n_in,
                              void* d_out, int out_size, void* d_ws, size_t ws_size,
                              hipStream_t stream)
{
    const float* ctrl       = (const float*)d_in[0];  // (256,10,2)
    const float* features   = (const float*)d_in[1];  // (256,3)
    const float* cholesky   = (const float*)d_in[2];  // (256,3)
    const float* opacity    = (const float*)d_in[3];  // (256,1)
    const float* depth      = (const float*)d_in[4];  // (256,1)
    const float* background = (const float*)d_in[5];  // (3,)
    float* out = (float*)d_out;                       // (256,256,3)

    // workspace layout (16B-aligned)
    char* w = (char*)d_ws;
    float*    recs    = (float*)   (w);                    // 524288 B
    unsigned* bboxp   = (unsigned*)(w + 524288);           //  65536 B
    float4*   partial = (float4*)  (w + 524288 + 65536);   // 8 MiB

    prep<<<NCURVES, GPER, 0, stream>>>(ctrl, features, cholesky, opacity, depth,
                                       recs, bboxp);
    render8<<<NTILES*SEGS, 256, 0, stream>>>(recs, bboxp, partial);
    combine<<<(IMG_W*IMG_H)/256, 256, 0, stream>>>(partial, background, out);
}